// Round 3
// baseline (1318.122 us; speedup 1.0000x reference)
//
#include <hip/hip_runtime.h>

#define NN 50000
#define EE 1600000
#define RR 16
#define NBASE 4
#define FINF 128
#define HD 128
#define NG 64
#define NCLS 2
#define NRSEG (NN*RR)   // 800000

typedef __attribute__((ext_vector_type(8))) short short8;
typedef __attribute__((ext_vector_type(4))) float f32x4;
typedef unsigned short u16;
typedef unsigned int u32;

__device__ __forceinline__ float bflo(u32 u){ return __builtin_bit_cast(float, u << 16); }
__device__ __forceinline__ float bfhi(u32 u){ return __builtin_bit_cast(float, u & 0xFFFF0000u); }
__device__ __forceinline__ u16 f2bf(float f){
  u32 u = __builtin_bit_cast(u32, f);
  u += 0x7FFFu + ((u >> 16) & 1u);
  return (u16)(u >> 16);
}
__device__ __forceinline__ u32 pack2(float a, float b){
  return (u32)f2bf(a) | ((u32)f2bf(b) << 16);
}
// dtype-dispatched scalar load of a "float" input array
__device__ __forceinline__ float ldf(const void* p, int i, int isbf){
  return isbf ? bflo((u32)((const u16*)p)[i]) : ((const float*)p)[i];
}

// ---------------- dtype detector ----------------
// bf16-packed N(0,1) data: low half of each u32 is a bf16 with exponent field
// in ~[100,129] for essentially every sample -> ~256/256 votes.
// fp32 data: low half is mantissa bits -> bits14..7 uniform -> ~30/256 votes.
__global__ void k_detect(const u32* __restrict__ xw, int* __restrict__ flag){
  __shared__ int votes;
  if (threadIdx.x == 0) votes = 0;
  __syncthreads();
  u32 w = xw[threadIdx.x];
  int e = (w >> 7) & 0xFF;
  if (e >= 100 && e <= 129) atomicAdd(&votes, 1);
  __syncthreads();
  if (threadIdx.x == 0) flag[0] = (votes >= 192) ? 1 : 0;
}

// ---------------- CSR build ----------------

__global__ void k_hist(const int* __restrict__ dst, const int* __restrict__ et,
                       int* __restrict__ cnt){
  int e = blockIdx.x*256 + threadIdx.x;
  if (e < EE) atomicAdd(&cnt[dst[e]*RR + et[e]], 1);
}

__global__ void k_scan1(const int* __restrict__ cnt, int* __restrict__ off,
                        int* __restrict__ bsum){
  __shared__ int sh[256];
  int tid = threadIdx.x;
  int i = blockIdx.x*256 + tid;
  int v = (i < NRSEG) ? cnt[i] : 0;
  sh[tid] = v; __syncthreads();
  for (int d=1; d<256; d<<=1){
    int t = (tid >= d) ? sh[tid-d] : 0;
    __syncthreads();
    sh[tid] += t;
    __syncthreads();
  }
  if (i < NRSEG) off[i] = sh[tid] - v;       // exclusive, block-local
  if (tid == 255) bsum[blockIdx.x] = sh[255];
}

__global__ void k_scan2(int* __restrict__ bsum, int nb){
  __shared__ int sh[256];
  __shared__ int carry;
  int tid = threadIdx.x;
  if (tid == 0) carry = 0;
  __syncthreads();
  for (int base=0; base<nb; base+=256){
    int i = base + tid;
    int v = (i < nb) ? bsum[i] : 0;
    int orig = v;
    sh[tid] = v; __syncthreads();
    for (int d=1; d<256; d<<=1){
      int t = (tid >= d) ? sh[tid-d] : 0;
      __syncthreads();
      sh[tid] += t;
      __syncthreads();
    }
    int total = sh[255];
    int excl = sh[tid] - orig + carry;
    if (i < nb) bsum[i] = excl;
    __syncthreads();
    if (tid == 0) carry += total;
    __syncthreads();
  }
}

__global__ void k_scan3(const int* __restrict__ cnt, int* __restrict__ off,
                        const int* __restrict__ bsum){
  int i = blockIdx.x*256 + threadIdx.x;
  if (i < NRSEG){
    int o = off[i] + bsum[blockIdx.x];
    off[i] = o;
    if (i == NRSEG-1) off[NRSEG] = o + cnt[i];
  }
}

// consumes cnt (decrements to zero); esrc gets each segment's sources contiguously
__global__ void k_scatter(const int* __restrict__ src, const int* __restrict__ dst,
                          const int* __restrict__ et, const int* __restrict__ off,
                          int* __restrict__ cnt, int* __restrict__ esrc){
  int e = blockIdx.x*256 + threadIdx.x;
  if (e < EE){
    int seg = dst[e]*RR + et[e];
    int p = atomicSub(&cnt[seg], 1) - 1;
    esrc[off[seg] + p] = src[e];
  }
}

// ---------------- weights: WT[r][o][i] = sum_b comp[r,b]*bases[b][i][o]; WT[16]=root^T ----

__global__ void k_weights(const void* __restrict__ bases, const void* __restrict__ comp,
                          const void* __restrict__ root, u16* __restrict__ WT,
                          const int* __restrict__ flagp){
  int idx = blockIdx.x*256 + threadIdx.x;
  if (idx >= 17*16384) return;
  int isbf = flagp[0];
  int r = idx >> 14;
  int o = (idx >> 7) & 127;
  int i = idx & 127;
  float v;
  if (r < RR){
    v = 0.f;
    #pragma unroll
    for (int b=0;b<NBASE;b++)
      v += ldf(comp, r*NBASE+b, isbf) * ldf(bases, (b*FINF + i)*HD + o, isbf);
  } else {
    v = ldf(root, i*HD + o, isbf);
  }
  WT[idx] = f2bf(v);
}

// ---------------- fused aggregate + GEMM layer ----------------
// WG: 64 nodes, 256 threads (4 waves). Loop r=0..16 (16==root pass).
// A-tile [64][136] bf16 in LDS (segment means), B-tile = WT[r] [128][136].
// acc: 64x128 fp32 over 4 waves (wave w -> rows 16w..16w+15), 8 col-tiles.

#define TN 64

__global__ __launch_bounds__(256) void k_layer(
    const void* __restrict__ xin, const u16* __restrict__ WT,
    const void* __restrict__ bias, const int* __restrict__ off,
    const int* __restrict__ esrc, u16* __restrict__ hout,
    const int* __restrict__ flagp, int xin_is_input, int relu)
{
  __shared__ __align__(16) u16 Abuf[TN*136];
  __shared__ __align__(16) u16 Bbuf[128*136];
  int tid = threadIdx.x;
  int n0 = blockIdx.x * TN;

  int isbf_in = flagp[0];                    // dtype of harness float inputs
  int isbf_x  = xin_is_input ? isbf_in : 1;  // h buffers are always bf16

  int ai = tid >> 2;          // node slot 0..63
  int ap = tid & 3;           // feature quarter (32 feats)
  int node = n0 + ai;

  int wv = tid >> 6;
  int lane = tid & 63;
  int mrow = lane & 15;
  int quad = lane >> 4;

  f32x4 acc[8];
  #pragma unroll
  for (int c=0;c<8;c++){ f32x4 z = {0.f,0.f,0.f,0.f}; acc[c] = z; }

  for (int rr=0; rr<17; ++rr){
    __syncthreads();   // LDS free from previous iteration's MFMA reads
    // stage B = WT[rr], padded stride 136. 256 threads x 128B = full 32KB tile.
    {
      int brow = tid >> 1;
      int bh = tid & 1;
      const uint4* s = (const uint4*)(WT + rr*16384 + brow*128 + bh*64);
      uint4* d = (uint4*)(Bbuf + brow*136 + bh*64);
      #pragma unroll
      for (int q=0;q<8;q++) d[q] = s[q];
    }
    // aggregate A: mean over edges of segment (node, rr); rr==16 -> x[node] itself
    {
      float facc[32];
      #pragma unroll
      for (int k=0;k<32;k++) facc[k] = 0.f;
      float scale = 0.f;
      if (node < NN){
        int e0, e1;
        if (rr < RR){
          int seg = node*RR + rr; e0 = off[seg]; e1 = off[seg+1];
          int c = e1 - e0;
          scale = 1.0f / (float)(c > 0 ? c : 1);
        } else { e0 = 0; e1 = 1; scale = 1.f; }
        for (int e=e0; e<e1; ++e){
          int s = (rr < RR) ? esrc[e] : node;
          if (isbf_x){
            const uint4* xr = (const uint4*)((const u16*)xin + (size_t)s*HD + ap*32);
            #pragma unroll
            for (int q=0;q<4;q++){
              uint4 v = xr[q];
              facc[q*8+0] += bflo(v.x); facc[q*8+1] += bfhi(v.x);
              facc[q*8+2] += bflo(v.y); facc[q*8+3] += bfhi(v.y);
              facc[q*8+4] += bflo(v.z); facc[q*8+5] += bfhi(v.z);
              facc[q*8+6] += bflo(v.w); facc[q*8+7] += bfhi(v.w);
            }
          } else {
            const float4* xr = (const float4*)((const float*)xin + (size_t)s*HD + ap*32);
            #pragma unroll
            for (int q=0;q<8;q++){
              float4 v = xr[q];
              facc[q*4+0] += v.x; facc[q*4+1] += v.y;
              facc[q*4+2] += v.z; facc[q*4+3] += v.w;
            }
          }
        }
      }
      uint4* arow = (uint4*)(Abuf + ai*136 + ap*32);
      #pragma unroll
      for (int q=0;q<4;q++){
        uint4 pv;
        pv.x = pack2(facc[q*8+0]*scale, facc[q*8+1]*scale);
        pv.y = pack2(facc[q*8+2]*scale, facc[q*8+3]*scale);
        pv.z = pack2(facc[q*8+4]*scale, facc[q*8+5]*scale);
        pv.w = pack2(facc[q*8+6]*scale, facc[q*8+7]*scale);
        arow[q] = pv;
      }
    }
    __syncthreads();
    // MFMA: C[64x128] += A[64x128] @ W[r][128x128]
    short8 af[4];
    #pragma unroll
    for (int ks=0;ks<4;ks++)
      af[ks] = *(const short8*)(Abuf + (wv*16 + mrow)*136 + ks*32 + quad*8);
    #pragma unroll
    for (int c=0;c<8;c++){
      #pragma unroll
      for (int ks=0;ks<4;ks++){
        short8 bf = *(const short8*)(Bbuf + (c*16 + mrow)*136 + ks*32 + quad*8);
        acc[c] = __builtin_amdgcn_mfma_f32_16x16x32_bf16(af[ks], bf, acc[c], 0, 0, 0);
      }
    }
  }
  // epilogue: bias (+relu), NaN firewall, store bf16
  #pragma unroll
  for (int c=0;c<8;c++){
    int col = c*16 + mrow;
    float bv = ldf(bias, col, isbf_in);
    #pragma unroll
    for (int rg=0;rg<4;rg++){
      int row = wv*16 + quad*4 + rg;
      int n = n0 + row;
      if (n < NN){
        float v = acc[c][rg] + bv;
        if (relu) v = fmaxf(v, 0.f);
        if (!(v == v)) v = 0.f;     // diagnostic firewall: no-op on correct path
        hout[(size_t)n*HD + col] = f2bf(v);
      }
    }
  }
}

// ---------------- global mean pool + concat + linear head ----------------

__global__ __launch_bounds__(128) void k_pool_head(
    const u16* __restrict__ h, const int* __restrict__ batch,
    const int* __restrict__ rlab, const void* __restrict__ rel_emb,
    const void* __restrict__ lin_w, const void* __restrict__ lin_b,
    void* __restrict__ out, const int* __restrict__ flagp)
{
  int g = blockIdx.x;
  int isbf = flagp[0];
  __shared__ int bounds[2];
  __shared__ float red[4];
  if (threadIdx.x == 0){
    int lo=0, hi=NN;
    while (lo < hi){ int m=(lo+hi)>>1; if (batch[m] < g) lo=m+1; else hi=m; }
    bounds[0] = lo;
    int lo2=lo, hi2=NN;
    while (lo2 < hi2){ int m=(lo2+hi2)>>1; if (batch[m] < g+1) lo2=m+1; else hi2=m; }
    bounds[1] = lo2;
  }
  __syncthreads();
  int lo = bounds[0], hi = bounds[1];
  int f = threadIdx.x;   // 0..127
  float acc = 0.f;
  for (int n=lo; n<hi; ++n) acc += bflo((u32)h[(size_t)n*HD + f]);
  int cn = hi - lo;
  float pooled = acc / (float)(cn > 0 ? cn : 1);
  int rl = rlab[g];
  float re = ldf(rel_emb, rl*HD + f, isbf);
  float v0 = pooled * ldf(lin_w, f*NCLS+0, isbf) + re * ldf(lin_w, (HD+f)*NCLS+0, isbf);
  float v1 = pooled * ldf(lin_w, f*NCLS+1, isbf) + re * ldf(lin_w, (HD+f)*NCLS+1, isbf);
  #pragma unroll
  for (int o=32;o>0;o>>=1){ v0 += __shfl_down(v0,o); v1 += __shfl_down(v1,o); }
  int ln = threadIdx.x & 63, wvv = threadIdx.x >> 6;
  if (ln == 0){ red[wvv*2] = v0; red[wvv*2+1] = v1; }
  __syncthreads();
  if (threadIdx.x == 0){
    float o0 = red[0] + red[2] + ldf(lin_b, 0, isbf);
    float o1 = red[1] + red[3] + ldf(lin_b, 1, isbf);
    if (isbf){
      ((u16*)out)[g*NCLS+0] = f2bf(o0);
      ((u16*)out)[g*NCLS+1] = f2bf(o1);
    } else {
      ((float*)out)[g*NCLS+0] = o0;
      ((float*)out)[g*NCLS+1] = o1;
    }
  }
}

// ---------------- launch ----------------

extern "C" void kernel_launch(void* const* d_in, const int* in_sizes, int n_in,
                              void* d_out, int out_size, void* d_ws, size_t ws_size,
                              hipStream_t stream)
{
  (void)in_sizes; (void)n_in; (void)out_size; (void)ws_size;
  const void* x      = d_in[0];
  const int* eidx    = (const int*)d_in[1];
  const int* etype   = (const int*)d_in[2];
  const int* batch   = (const int*)d_in[3];
  const int* rlab    = (const int*)d_in[4];
  const void* rel_emb = d_in[6];
  const void* basesA[3] = {d_in[7],  d_in[11], d_in[15]};
  const void* compA[3]  = {d_in[8],  d_in[12], d_in[16]};
  const void* rootA[3]  = {d_in[9],  d_in[13], d_in[17]};
  const void* biasA[3]  = {d_in[10], d_in[14], d_in[18]};
  const void* lin_w  = d_in[19];
  const void* lin_b  = d_in[20];

  char* p = (char*)d_ws;
  auto alloc = [&](size_t bytes)->char*{ char* r = p; p += (bytes + 255) & ~(size_t)255; return r; };
  int*   flag   = (int*)  alloc(256);
  int*   cnt    = (int*)  alloc((size_t)NRSEG*4);
  int*   off    = (int*)  alloc((size_t)(NRSEG+1)*4);
  int*   esrc   = (int*)  alloc((size_t)EE*4);
  int*   bsum   = (int*)  alloc(4096*4);
  u16*   WT     = (u16*)  alloc((size_t)17*16384*2);
  u16*   h1     = (u16*)  alloc((size_t)NN*HD*2);
  u16*   h2     = (u16*)  alloc((size_t)NN*HD*2);

  const int* src_in = eidx;        // edge_index[0]
  const int* dst_in = eidx + EE;   // edge_index[1]

  k_detect <<<1, 256, 0, stream>>>((const u32*)x, flag);
  hipMemsetAsync(cnt, 0, (size_t)NRSEG*4, stream);
  k_hist   <<<EE/256,    256, 0, stream>>>(dst_in, etype, cnt);
  k_scan1  <<<NRSEG/256, 256, 0, stream>>>(cnt, off, bsum);
  k_scan2  <<<1,         256, 0, stream>>>(bsum, NRSEG/256);
  k_scan3  <<<NRSEG/256, 256, 0, stream>>>(cnt, off, bsum);
  k_scatter<<<EE/256,    256, 0, stream>>>(src_in, dst_in, etype, off, cnt, esrc);

  const void* xin = x;
  u16* houts[3] = {h1, h2, h1};
  for (int l=0;l<3;l++){
    k_weights<<<1088, 256, 0, stream>>>(basesA[l], compA[l], rootA[l], WT, flag);
    k_layer<<<(NN + TN - 1)/TN, 256, 0, stream>>>(xin, WT, biasA[l], off, esrc,
                                                  houts[l], flag, (l == 0) ? 1 : 0,
                                                  (l < 2) ? 1 : 0);
    xin = houts[l];
  }
  k_pool_head<<<NG, 128, 0, stream>>>(houts[2], batch, rlab, rel_emb, lin_w, lin_b,
                                      d_out, flag);
}